// Round 7
// baseline (2410.308 us; speedup 1.0000x reference)
//
#include <hip/hip_runtime.h>
#include <hip/hip_bf16.h>

// ---------------------------------------------------------------------------
// SwinBlock for MI355X — split-bf16 (bf16x3) MFMA GEMMs, fp32-class accuracy.
// B=32 H=W=56 C=192 ws=7 shift=3 NH=6 hd=32; T=100352 token-rows.
// GEMMs run as D = Ah*Bh + Ah*Bl + Al*Bh on v_mfma_f32_16x16x32_bf16.
// A-operands pre-split to bf16 hi/lo by producer kernels; weights pre-split
// + transposed ([N][K]) once per call into workspace (~1.7 MB).
// Chunked over windows / rows to adapt to ws_size (constant -> capture-safe).
// ---------------------------------------------------------------------------

#define T_ROWS 100352
#define C_DIM  192
#define N_WIN  2048

typedef __attribute__((ext_vector_type(8))) short short8;
typedef __attribute__((ext_vector_type(4))) float f32x4;

// window token r=(w,n) -> image pixel index (gather & scatter use same map)
__device__ __forceinline__ int map_token(int r) {
    int w = r / 49, n = r % 49;
    int b = w >> 6, widx = w & 63;
    int wi = widx >> 3, wj = widx & 7;
    int pi = n / 7, pj = n % 7;
    int row = wi * 7 + pi + 3; if (row >= 56) row -= 56;
    int col = wj * 7 + pj + 3; if (col >= 56) col -= 56;
    return b * 3136 + row * 56 + col;
}

// split fp32 -> bf16 hi (truncate) + bf16 lo (truncate of exact remainder)
__device__ __forceinline__ void bsplit(float a, ushort& h, ushort& l) {
    unsigned u = __float_as_uint(a);
    h = (ushort)(u >> 16);
    float hf = __uint_as_float(u & 0xFFFF0000u);
    l = (ushort)(__float_as_uint(a - hf) >> 16);
}

// ---------------- weight split: W[K][N] fp32 -> Wt_hi/lo [N][K] bf16 ---------
__global__ __launch_bounds__(256) void split_w(
        const float* __restrict__ W, ushort* __restrict__ th,
        ushort* __restrict__ tl, int K, int N) {
    int idx = blockIdx.x * 256 + threadIdx.x;
    if (idx >= K * N) return;
    int k = idx / N, n = idx - k * N;
    ushort h, l; bsplit(W[idx], h, l);
    th[(size_t)n * K + k] = h;
    tl[(size_t)n * K + k] = l;
}

// ---------------- LN1 + shifted-window gather -> bf16 hi/lo ------------------
__global__ __launch_bounds__(256) void ln1_split(
        const float* __restrict__ x, const float* __restrict__ g,
        const float* __restrict__ b, ushort* __restrict__ oh,
        ushort* __restrict__ ol, int row_off) {
    int r    = blockIdx.x * 4 + (threadIdx.x >> 6);
    int lane = threadIdx.x & 63;
    int src  = map_token(row_off + r);
    const float* sp = x + (size_t)src * C_DIM;
    float v0 = sp[lane], v1 = sp[lane + 64], v2 = sp[lane + 128];
    float s  = v0 + v1 + v2;
    float s2 = v0 * v0 + v1 * v1 + v2 * v2;
    #pragma unroll
    for (int off = 32; off; off >>= 1) {
        s  += __shfl_xor(s,  off);
        s2 += __shfl_xor(s2, off);
    }
    float mu   = s * (1.0f / 192.0f);
    float var  = s2 * (1.0f / 192.0f) - mu * mu;
    float rstd = rsqrtf(var + 1e-5f);
    float v[3] = {v0, v1, v2};
    #pragma unroll
    for (int j = 0; j < 3; ++j) {
        int c = lane + 64 * j;
        float val = (v[j] - mu) * rstd * g[c] + b[c];
        ushort h, l; bsplit(val, h, l);
        oh[(size_t)r * C_DIM + c] = h;
        ol[(size_t)r * C_DIM + c] = l;
    }
}

// ---------------- LN2 -> bf16 hi/lo (row-aligned) ----------------------------
__global__ __launch_bounds__(256) void ln2_split(
        const float* __restrict__ hsrc, const float* __restrict__ g,
        const float* __restrict__ b, ushort* __restrict__ oh,
        ushort* __restrict__ ol) {
    int r    = blockIdx.x * 4 + (threadIdx.x >> 6);
    int lane = threadIdx.x & 63;
    const float* sp = hsrc + (size_t)r * C_DIM;
    float v0 = sp[lane], v1 = sp[lane + 64], v2 = sp[lane + 128];
    float s  = v0 + v1 + v2;
    float s2 = v0 * v0 + v1 * v1 + v2 * v2;
    #pragma unroll
    for (int off = 32; off; off >>= 1) {
        s  += __shfl_xor(s,  off);
        s2 += __shfl_xor(s2, off);
    }
    float mu   = s * (1.0f / 192.0f);
    float var  = s2 * (1.0f / 192.0f) - mu * mu;
    float rstd = rsqrtf(var + 1e-5f);
    float v[3] = {v0, v1, v2};
    #pragma unroll
    for (int j = 0; j < 3; ++j) {
        int c = lane + 64 * j;
        float val = (v[j] - mu) * rstd * g[c] + b[c];
        ushort h, l; bsplit(val, h, l);
        oh[(size_t)r * C_DIM + c] = h;
        ol[(size_t)r * C_DIM + c] = l;
    }
}

// ---------------- split-bf16 MFMA GEMM --------------------------------------
// BM=256, BN=64, BK=32, 256 threads = 4 waves, each wave 64(M)x64(N).
// A: [M][K] bf16 hi/lo (global, pre-split); B: [N][K] bf16 hi/lo (pre-split).
// MODE 0: C fp32 = acc + bias                      (qkv -> qkvc, stride 576)
// MODE 1: C[map_token(row_off+r)] = acc+bias+res   (proj -> d_out scatter)
// MODE 2: gelu(acc+bias) -> split -> Ch/Cl bf16    (mlp1 -> hidden)
// MODE 3: C = acc + bias + res[r]                  (mlp2 -> d_out rows)
template<int MODE>
__global__ __launch_bounds__(256, 2) void gemm_mfma(
        const ushort* __restrict__ Ah, const ushort* __restrict__ Al,
        const ushort* __restrict__ Bh, const ushort* __restrict__ Bl,
        const float* __restrict__ bias,
        float* __restrict__ C, ushort* __restrict__ Ch, ushort* __restrict__ Cl,
        int K, int N, int Cstride,
        const float* __restrict__ res, int row_off) {
    __shared__ ushort lA[2][256][32];   // [hi/lo][m][k], granule-swizzled
    __shared__ ushort lB[2][64][32];
    const int tid = threadIdx.x;
    const int m0  = blockIdx.y * 256;
    const int n0  = blockIdx.x * 64;
    const int w   = tid >> 6;
    const int lane = tid & 63;
    const int l15 = lane & 15, l4 = lane >> 4;

    // A staging: thread owns row `tid`, 4 granules of 8 ushorts per array
    const ushort* apH = Ah + (size_t)(m0 + tid) * K;
    const ushort* apL = Al + (size_t)(m0 + tid) * K;
    // B staging: thread owns 2 of 512 granules (64 rows x 4 q x 2 arrays)
    const int g0 = tid * 2, g1 = g0 + 1;
    const int ba0 = g0 >> 8, br0 = (g0 & 255) >> 2, bq0 = g0 & 3;
    const int ba1 = g1 >> 8, br1 = (g1 & 255) >> 2, bq1 = g1 & 3;
    const ushort* bp0 = (ba0 ? Bl : Bh) + (size_t)(n0 + br0) * K + bq0 * 8;
    const ushort* bp1 = (ba1 ? Bl : Bh) + (size_t)(n0 + br1) * K + bq1 * 8;

    f32x4 acc[4][4];
    #pragma unroll
    for (int i = 0; i < 4; ++i)
        #pragma unroll
        for (int j = 0; j < 4; ++j) acc[i][j] = (f32x4){0.f, 0.f, 0.f, 0.f};

    uint4 ra[2][4], rb[2];
    auto stage_load = [&](int k0) {
        #pragma unroll
        for (int q = 0; q < 4; ++q) {
            ra[0][q] = *(const uint4*)(apH + k0 + q * 8);
            ra[1][q] = *(const uint4*)(apL + k0 + q * 8);
        }
        rb[0] = *(const uint4*)(bp0 + k0);
        rb[1] = *(const uint4*)(bp1 + k0);
    };
    auto stage_write = [&]() {
        #pragma unroll
        for (int q = 0; q < 4; ++q) {
            *(uint4*)&lA[0][tid][(q ^ (tid & 3)) * 8] = ra[0][q];
            *(uint4*)&lA[1][tid][(q ^ (tid & 3)) * 8] = ra[1][q];
        }
        *(uint4*)&lB[ba0][br0][(bq0 ^ (br0 & 3)) * 8] = rb[0];
        *(uint4*)&lB[ba1][br1][(bq1 ^ (br1 & 3)) * 8] = rb[1];
    };

    stage_load(0);
    stage_write();
    __syncthreads();

    const int nt = K >> 5;
    for (int t = 0; t < nt; ++t) {
        if (t + 1 < nt) stage_load((t + 1) << 5);   // issue early (T14)
        short8 ah[4], al[4], bh[4], bl[4];
        #pragma unroll
        for (int mi = 0; mi < 4; ++mi) {
            const int r  = w * 64 + mi * 16 + l15;
            const int gg = (l4 ^ (r & 3)) * 8;
            ah[mi] = *(const short8*)&lA[0][r][gg];
            al[mi] = *(const short8*)&lA[1][r][gg];
        }
        #pragma unroll
        for (int ni = 0; ni < 4; ++ni) {
            const int r  = ni * 16 + l15;
            const int gg = (l4 ^ (r & 3)) * 8;
            bh[ni] = *(const short8*)&lB[0][r][gg];
            bl[ni] = *(const short8*)&lB[1][r][gg];
        }
        #pragma unroll
        for (int mi = 0; mi < 4; ++mi)
            #pragma unroll
            for (int ni = 0; ni < 4; ++ni) {
                acc[mi][ni] = __builtin_amdgcn_mfma_f32_16x16x32_bf16(
                    ah[mi], bh[ni], acc[mi][ni], 0, 0, 0);
                acc[mi][ni] = __builtin_amdgcn_mfma_f32_16x16x32_bf16(
                    ah[mi], bl[ni], acc[mi][ni], 0, 0, 0);
                acc[mi][ni] = __builtin_amdgcn_mfma_f32_16x16x32_bf16(
                    al[mi], bh[ni], acc[mi][ni], 0, 0, 0);
            }
        if (t + 1 < nt) {
            __syncthreads();        // all reads of lA/lB done
            stage_write();
            __syncthreads();        // new tile visible
        }
    }

    // epilogue: frag (mi,ni): rows w*64+mi*16 + l4*4+reg, col ni*16+l15
    #pragma unroll
    for (int ni = 0; ni < 4; ++ni) {
        const int gcol = n0 + ni * 16 + l15;
        const float bv = bias[gcol];
        #pragma unroll
        for (int mi = 0; mi < 4; ++mi) {
            #pragma unroll
            for (int reg = 0; reg < 4; ++reg) {
                const int grow = m0 + w * 64 + mi * 16 + l4 * 4 + reg;
                float o = acc[mi][ni][reg] + bv;
                if (MODE == 0) {
                    C[(size_t)grow * Cstride + gcol] = o;
                } else if (MODE == 1) {
                    const int dst = map_token(row_off + grow);
                    C[(size_t)dst * C_DIM + gcol] =
                        o + res[(size_t)dst * C_DIM + gcol];
                } else if (MODE == 2) {
                    o = 0.5f * o * (1.0f + erff(o * 0.70710678118654752f));
                    ushort h, l; bsplit(o, h, l);
                    Ch[(size_t)grow * Cstride + gcol] = h;
                    Cl[(size_t)grow * Cstride + gcol] = l;
                } else {
                    C[(size_t)grow * Cstride + gcol] =
                        o + res[(size_t)grow * C_DIM + gcol];
                }
            }
        }
    }
}

// ---------------- window attention (fp32, unchanged math) --------------------
// Reads chunk-local qkv fp32; writes output split to bf16 hi/lo arrays.
__global__ __launch_bounds__(256) void attn_kernel(
        const float* __restrict__ qkv, const float* __restrict__ rpb,
        ushort* __restrict__ oh, ushort* __restrict__ ol, int w0) {
    const int lw = blockIdx.x / 6;
    const int h  = blockIdx.x % 6;
    const int w  = w0 + lw;
    __shared__ float q[49][33], k[49][33], v[49][33];
    __shared__ float S[49][50];
    __shared__ float rsum[49];
    const int tid = threadIdx.x;
    const float scale = 0.17677669529663687f;
    const float* base = qkv + (size_t)lw * 49 * 576 + h * 32;
    for (int i = tid; i < 49 * 32; i += 256) {
        const int n = i >> 5, c = i & 31;
        q[n][c] = base[n * 576 + c];
        k[n][c] = base[n * 576 + 192 + c];
        v[n][c] = base[n * 576 + 384 + c];
    }
    __syncthreads();
    const int widx = w & 63;
    const int wi = widx >> 3, wj = widx & 7;
    for (int e = tid; e < 49 * 49; e += 256) {
        const int n = e / 49, m = e % 49;
        float acc = 0.f;
        #pragma unroll
        for (int c = 0; c < 32; ++c) acc = fmaf(q[n][c], k[m][c], acc);
        acc *= scale;
        const int pin = n / 7, pjn = n % 7, pim = m / 7, pjm = m % 7;
        acc += rpb[((pin - pim + 6) * 13 + (pjn - pjm + 6)) * 6 + h];
        const int rn = wi * 7 + pin, cn = wj * 7 + pjn;
        const int rm = wi * 7 + pim, cm = wj * 7 + pjm;
        const int zn = (rn < 49 ? 0 : (rn < 53 ? 1 : 2)) * 3 + (cn < 49 ? 0 : (cn < 53 ? 1 : 2));
        const int zm = (rm < 49 ? 0 : (rm < 53 ? 1 : 2)) * 3 + (cm < 49 ? 0 : (cm < 53 ? 1 : 2));
        if (zn != zm) acc -= 100.0f;
        S[n][m] = acc;
    }
    __syncthreads();
    if (tid < 49) {
        float mx = -1e30f;
        #pragma unroll 7
        for (int m2 = 0; m2 < 49; ++m2) mx = fmaxf(mx, S[tid][m2]);
        float sum = 0.f;
        #pragma unroll 7
        for (int m2 = 0; m2 < 49; ++m2) {
            const float e2 = expf(S[tid][m2] - mx);
            S[tid][m2] = e2;
            sum += e2;
        }
        rsum[tid] = 1.0f / sum;
    }
    __syncthreads();
    for (int e = tid; e < 49 * 32; e += 256) {
        const int n = e >> 5, c = e & 31;
        float acc = 0.f;
        #pragma unroll 7
        for (int m2 = 0; m2 < 49; ++m2) acc = fmaf(S[n][m2], v[m2][c], acc);
        ushort hh, ll; bsplit(acc * rsum[n], hh, ll);
        oh[((size_t)lw * 49 + n) * C_DIM + h * 32 + c] = hh;
        ol[((size_t)lw * 49 + n) * C_DIM + h * 32 + c] = ll;
    }
}

// ---------------------------------------------------------------------------
extern "C" void kernel_launch(void* const* d_in, const int* in_sizes, int n_in,
                              void* d_out, int out_size, void* d_ws, size_t ws_size,
                              hipStream_t stream) {
    const float* x      = (const float*)d_in[0];
    const float* n1g    = (const float*)d_in[1];
    const float* n1b    = (const float*)d_in[2];
    const float* n2g    = (const float*)d_in[3];
    const float* n2b    = (const float*)d_in[4];
    const float* qkv_w  = (const float*)d_in[5];
    const float* qkv_b  = (const float*)d_in[6];
    const float* proj_w = (const float*)d_in[7];
    const float* proj_b = (const float*)d_in[8];
    const float* rpb    = (const float*)d_in[9];
    const float* mlp_w1 = (const float*)d_in[10];
    const float* mlp_b1 = (const float*)d_in[11];
    const float* mlp_w2 = (const float*)d_in[12];
    const float* mlp_b2 = (const float*)d_in[13];
    float* out = (float*)d_out;

    // ---- workspace layout: split weights (1.73 MB) then shared chunk buffer
    ushort* btq_h  = (ushort*)d_ws;
    ushort* btq_l  = btq_h + 110592;
    ushort* btp_h  = btq_l + 110592;
    ushort* btp_l  = btp_h + 36864;
    ushort* btm1_h = btp_l + 36864;
    ushort* btm1_l = btm1_h + 147456;
    ushort* btm2_h = btm1_l + 147456;
    ushort* btm2_l = btm2_h + 147456;
    char* chunkbuf = (char*)(btm2_l + 147456);
    const size_t btBytes = (size_t)2 * 884736;
    const size_t avail = ws_size > btBytes ? ws_size - btBytes : 0;

    // chunk counts from ws_size (constant across calls -> capture-safe);
    // winC and rowsM must stay multiples of 256 for the BM=256 GEMM
    int nc = 1;
    while (nc < 8 && (size_t)(N_WIN / nc) * 49 * 3072 > avail) nc <<= 1;
    int nm = 1;
    while (nm < 8 && (size_t)(T_ROWS / nm) * 3840 > avail) nm <<= 1;
    const int winC  = N_WIN / nc;
    const int rowsC = winC * 49;
    const int rowsM = T_ROWS / nm;

    // attention-chunk pointers
    ushort* Axh  = (ushort*)chunkbuf;
    ushort* Axl  = Axh + (size_t)rowsC * C_DIM;
    float*  qkvc = (float*)(Axl + (size_t)rowsC * C_DIM);
    // mlp-chunk pointers (same region, different phase)
    ushort* Lh = (ushort*)chunkbuf;
    ushort* Ll = Lh + (size_t)rowsM * C_DIM;
    ushort* Hh = Ll + (size_t)rowsM * C_DIM;
    ushort* Hl = Hh + (size_t)rowsM * 768;

    const dim3 blk(256);

    // 0. split + transpose the four weight matrices
    split_w<<<dim3((192 * 576 + 255) / 256), blk, 0, stream>>>(qkv_w,  btq_h,  btq_l,  192, 576);
    split_w<<<dim3((192 * 192 + 255) / 256), blk, 0, stream>>>(proj_w, btp_h,  btp_l,  192, 192);
    split_w<<<dim3((192 * 768 + 255) / 256), blk, 0, stream>>>(mlp_w1, btm1_h, btm1_l, 192, 768);
    split_w<<<dim3((768 * 192 + 255) / 256), blk, 0, stream>>>(mlp_w2, btm2_h, btm2_l, 768, 192);

    // 1-4. attention path, chunked over windows
    for (int c = 0; c < nc; ++c) {
        const int row_off = c * rowsC;
        ln1_split<<<dim3(rowsC / 4), blk, 0, stream>>>(x, n1g, n1b, Axh, Axl, row_off);
        gemm_mfma<0><<<dim3(9, rowsC / 256), blk, 0, stream>>>(
            Axh, Axl, btq_h, btq_l, qkv_b, qkvc, nullptr, nullptr,
            192, 576, 576, nullptr, row_off);
        attn_kernel<<<dim3(winC * 6), blk, 0, stream>>>(qkvc, rpb, Axh, Axl, c * winC);
        gemm_mfma<1><<<dim3(3, rowsC / 256), blk, 0, stream>>>(
            Axh, Axl, btp_h, btp_l, proj_b, out, nullptr, nullptr,
            192, 192, 192, x, row_off);
    }

    // 5-7. MLP path, chunked over rows; finishes d_out rows in place
    for (int c = 0; c < nm; ++c) {
        const size_t ro = (size_t)c * rowsM;
        ln2_split<<<dim3(rowsM / 4), blk, 0, stream>>>(
            out + ro * C_DIM, n2g, n2b, Lh, Ll);
        gemm_mfma<2><<<dim3(12, rowsM / 256), blk, 0, stream>>>(
            Lh, Ll, btm1_h, btm1_l, mlp_b1, nullptr, Hh, Hl,
            192, 768, 768, nullptr, 0);
        gemm_mfma<3><<<dim3(3, rowsM / 256), blk, 0, stream>>>(
            Hh, Hl, btm2_h, btm2_l, mlp_b2, out + ro * C_DIM, nullptr, nullptr,
            768, 192, 192, out + ro * C_DIM, 0);
    }
}

// Round 8
// 1451.738 us; speedup vs baseline: 1.6603x; 1.6603x over previous
//
#include <hip/hip_runtime.h>
#include <hip/hip_bf16.h>

// ---------------------------------------------------------------------------
// SwinBlock for MI355X. Attention path: split-bf16 MFMA GEMMs (verified r7).
// MLP path: fully fused LN2+mlp1+GELU+mlp2+residual, hidden lives in LDS.
// bf16x3: D = Ah*Bh + Ah*Bl + Al*Bh on v_mfma_f32_16x16x32_bf16 (~fp32 acc).
// ---------------------------------------------------------------------------

#define T_ROWS 100352
#define C_DIM  192
#define N_WIN  2048

typedef __attribute__((ext_vector_type(8))) short short8;
typedef __attribute__((ext_vector_type(4))) float f32x4;

__device__ __forceinline__ int map_token(int r) {
    int w = r / 49, n = r % 49;
    int b = w >> 6, widx = w & 63;
    int wi = widx >> 3, wj = widx & 7;
    int pi = n / 7, pj = n % 7;
    int row = wi * 7 + pi + 3; if (row >= 56) row -= 56;
    int col = wj * 7 + pj + 3; if (col >= 56) col -= 56;
    return b * 3136 + row * 56 + col;
}

__device__ __forceinline__ void bsplit(float a, ushort& h, ushort& l) {
    unsigned u = __float_as_uint(a);
    h = (ushort)(u >> 16);
    float hf = __uint_as_float(u & 0xFFFF0000u);
    l = (ushort)(__float_as_uint(a - hf) >> 16);
}

// ---------------- weight split: W[K][N] fp32 -> Wt_hi/lo [N][K] bf16 ---------
__global__ __launch_bounds__(256) void split_w(
        const float* __restrict__ W, ushort* __restrict__ th,
        ushort* __restrict__ tl, int K, int N) {
    int idx = blockIdx.x * 256 + threadIdx.x;
    if (idx >= K * N) return;
    int k = idx / N, n = idx - k * N;
    ushort h, l; bsplit(W[idx], h, l);
    th[(size_t)n * K + k] = h;
    tl[(size_t)n * K + k] = l;
}

// ---------------- LN1 + shifted-window gather -> bf16 hi/lo ------------------
__global__ __launch_bounds__(256) void ln1_split(
        const float* __restrict__ x, const float* __restrict__ g,
        const float* __restrict__ b, ushort* __restrict__ oh,
        ushort* __restrict__ ol, int row_off) {
    int r    = blockIdx.x * 4 + (threadIdx.x >> 6);
    int lane = threadIdx.x & 63;
    int src  = map_token(row_off + r);
    const float* sp = x + (size_t)src * C_DIM;
    float v0 = sp[lane], v1 = sp[lane + 64], v2 = sp[lane + 128];
    float s  = v0 + v1 + v2;
    float s2 = v0 * v0 + v1 * v1 + v2 * v2;
    #pragma unroll
    for (int off = 32; off; off >>= 1) {
        s  += __shfl_xor(s,  off);
        s2 += __shfl_xor(s2, off);
    }
    float mu   = s * (1.0f / 192.0f);
    float var  = s2 * (1.0f / 192.0f) - mu * mu;
    float rstd = rsqrtf(var + 1e-5f);
    float v[3] = {v0, v1, v2};
    #pragma unroll
    for (int j = 0; j < 3; ++j) {
        int c = lane + 64 * j;
        float val = (v[j] - mu) * rstd * g[c] + b[c];
        ushort h, l; bsplit(val, h, l);
        oh[(size_t)r * C_DIM + c] = h;
        ol[(size_t)r * C_DIM + c] = l;
    }
}

// ---------------- per-row LN stats (mu, rstd) for LN2 ------------------------
__global__ __launch_bounds__(256) void ln_stats(
        const float* __restrict__ h, float* __restrict__ stats) {
    int row  = blockIdx.x * 4 + (threadIdx.x >> 6);
    int lane = threadIdx.x & 63;
    const float* sp = h + (size_t)row * C_DIM;
    float v0 = sp[lane], v1 = sp[lane + 64], v2 = sp[lane + 128];
    float s  = v0 + v1 + v2;
    float s2 = v0 * v0 + v1 * v1 + v2 * v2;
    #pragma unroll
    for (int off = 32; off; off >>= 1) {
        s  += __shfl_xor(s,  off);
        s2 += __shfl_xor(s2, off);
    }
    if (lane == 0) {
        float mu  = s * (1.0f / 192.0f);
        float var = s2 * (1.0f / 192.0f) - mu * mu;
        stats[(size_t)row * 2]     = mu;
        stats[(size_t)row * 2 + 1] = rsqrtf(var + 1e-5f);
    }
}

// ---------------- split-bf16 MFMA GEMM (attention path, verified r7) ---------
// MODE 0: C fp32 = acc + bias   (qkv -> qkvc, stride 576)
// MODE 1: C[map_token(row_off+r)] = acc+bias+res   (proj -> d_out scatter)
template<int MODE>
__global__ __launch_bounds__(256, 2) void gemm_mfma(
        const ushort* __restrict__ Ah, const ushort* __restrict__ Al,
        const ushort* __restrict__ Bh, const ushort* __restrict__ Bl,
        const float* __restrict__ bias,
        float* __restrict__ C,
        int K, int N, int Cstride,
        const float* __restrict__ res, int row_off) {
    __shared__ ushort lA[2][256][32];
    __shared__ ushort lB[2][64][32];
    const int tid = threadIdx.x;
    const int m0  = blockIdx.y * 256;
    const int n0  = blockIdx.x * 64;
    const int w   = tid >> 6;
    const int lane = tid & 63;
    const int l15 = lane & 15, l4 = lane >> 4;

    const ushort* apH = Ah + (size_t)(m0 + tid) * K;
    const ushort* apL = Al + (size_t)(m0 + tid) * K;
    const int g0 = tid * 2, g1 = g0 + 1;
    const int ba0 = g0 >> 8, br0 = (g0 & 255) >> 2, bq0 = g0 & 3;
    const int ba1 = g1 >> 8, br1 = (g1 & 255) >> 2, bq1 = g1 & 3;
    const ushort* bp0 = (ba0 ? Bl : Bh) + (size_t)(n0 + br0) * K + bq0 * 8;
    const ushort* bp1 = (ba1 ? Bl : Bh) + (size_t)(n0 + br1) * K + bq1 * 8;

    f32x4 acc[4][4];
    #pragma unroll
    for (int i = 0; i < 4; ++i)
        #pragma unroll
        for (int j = 0; j < 4; ++j) acc[i][j] = (f32x4){0.f, 0.f, 0.f, 0.f};

    uint4 ra[2][4], rb[2];
    auto stage_load = [&](int k0) {
        #pragma unroll
        for (int q = 0; q < 4; ++q) {
            ra[0][q] = *(const uint4*)(apH + k0 + q * 8);
            ra[1][q] = *(const uint4*)(apL + k0 + q * 8);
        }
        rb[0] = *(const uint4*)(bp0 + k0);
        rb[1] = *(const uint4*)(bp1 + k0);
    };
    auto stage_write = [&]() {
        #pragma unroll
        for (int q = 0; q < 4; ++q) {
            *(uint4*)&lA[0][tid][(q ^ (tid & 3)) * 8] = ra[0][q];
            *(uint4*)&lA[1][tid][(q ^ (tid & 3)) * 8] = ra[1][q];
        }
        *(uint4*)&lB[ba0][br0][(bq0 ^ (br0 & 3)) * 8] = rb[0];
        *(uint4*)&lB[ba1][br1][(bq1 ^ (br1 & 3)) * 8] = rb[1];
    };

    stage_load(0);
    stage_write();
    __syncthreads();

    const int nt = K >> 5;
    for (int t = 0; t < nt; ++t) {
        if (t + 1 < nt) stage_load((t + 1) << 5);
        short8 ah[4], al[4], bh[4], bl[4];
        #pragma unroll
        for (int mi = 0; mi < 4; ++mi) {
            const int r  = w * 64 + mi * 16 + l15;
            const int gg = (l4 ^ (r & 3)) * 8;
            ah[mi] = *(const short8*)&lA[0][r][gg];
            al[mi] = *(const short8*)&lA[1][r][gg];
        }
        #pragma unroll
        for (int ni = 0; ni < 4; ++ni) {
            const int r  = ni * 16 + l15;
            const int gg = (l4 ^ (r & 3)) * 8;
            bh[ni] = *(const short8*)&lB[0][r][gg];
            bl[ni] = *(const short8*)&lB[1][r][gg];
        }
        #pragma unroll
        for (int mi = 0; mi < 4; ++mi)
            #pragma unroll
            for (int ni = 0; ni < 4; ++ni) {
                acc[mi][ni] = __builtin_amdgcn_mfma_f32_16x16x32_bf16(
                    ah[mi], bh[ni], acc[mi][ni], 0, 0, 0);
                acc[mi][ni] = __builtin_amdgcn_mfma_f32_16x16x32_bf16(
                    ah[mi], bl[ni], acc[mi][ni], 0, 0, 0);
                acc[mi][ni] = __builtin_amdgcn_mfma_f32_16x16x32_bf16(
                    al[mi], bh[ni], acc[mi][ni], 0, 0, 0);
            }
        if (t + 1 < nt) {
            __syncthreads();
            stage_write();
            __syncthreads();
        }
    }

    #pragma unroll
    for (int ni = 0; ni < 4; ++ni) {
        const int gcol = n0 + ni * 16 + l15;
        const float bv = bias[gcol];
        #pragma unroll
        for (int mi = 0; mi < 4; ++mi) {
            #pragma unroll
            for (int reg = 0; reg < 4; ++reg) {
                const int grow = m0 + w * 64 + mi * 16 + l4 * 4 + reg;
                float o = acc[mi][ni][reg] + bv;
                if (MODE == 0) {
                    C[(size_t)grow * Cstride + gcol] = o;
                } else {
                    const int dst = map_token(row_off + grow);
                    C[(size_t)dst * C_DIM + gcol] =
                        o + res[(size_t)dst * C_DIM + gcol];
                }
            }
        }
    }
}

// ---------------- window attention (fp32, verified) --------------------------
__global__ __launch_bounds__(256) void attn_kernel(
        const float* __restrict__ qkv, const float* __restrict__ rpb,
        ushort* __restrict__ oh, ushort* __restrict__ ol, int w0) {
    const int lw = blockIdx.x / 6;
    const int h  = blockIdx.x % 6;
    const int w  = w0 + lw;
    __shared__ float q[49][33], k[49][33], v[49][33];
    __shared__ float S[49][50];
    __shared__ float rsum[49];
    const int tid = threadIdx.x;
    const float scale = 0.17677669529663687f;
    const float* base = qkv + (size_t)lw * 49 * 576 + h * 32;
    for (int i = tid; i < 49 * 32; i += 256) {
        const int n = i >> 5, c = i & 31;
        q[n][c] = base[n * 576 + c];
        k[n][c] = base[n * 576 + 192 + c];
        v[n][c] = base[n * 576 + 384 + c];
    }
    __syncthreads();
    const int widx = w & 63;
    const int wi = widx >> 3, wj = widx & 7;
    for (int e = tid; e < 49 * 49; e += 256) {
        const int n = e / 49, m = e % 49;
        float acc = 0.f;
        #pragma unroll
        for (int c = 0; c < 32; ++c) acc = fmaf(q[n][c], k[m][c], acc);
        acc *= scale;
        const int pin = n / 7, pjn = n % 7, pim = m / 7, pjm = m % 7;
        acc += rpb[((pin - pim + 6) * 13 + (pjn - pjm + 6)) * 6 + h];
        const int rn = wi * 7 + pin, cn = wj * 7 + pjn;
        const int rm = wi * 7 + pim, cm = wj * 7 + pjm;
        const int zn = (rn < 49 ? 0 : (rn < 53 ? 1 : 2)) * 3 + (cn < 49 ? 0 : (cn < 53 ? 1 : 2));
        const int zm = (rm < 49 ? 0 : (rm < 53 ? 1 : 2)) * 3 + (cm < 49 ? 0 : (cm < 53 ? 1 : 2));
        if (zn != zm) acc -= 100.0f;
        S[n][m] = acc;
    }
    __syncthreads();
    if (tid < 49) {
        float mx = -1e30f;
        #pragma unroll 7
        for (int m2 = 0; m2 < 49; ++m2) mx = fmaxf(mx, S[tid][m2]);
        float sum = 0.f;
        #pragma unroll 7
        for (int m2 = 0; m2 < 49; ++m2) {
            const float e2 = expf(S[tid][m2] - mx);
            S[tid][m2] = e2;
            sum += e2;
        }
        rsum[tid] = 1.0f / sum;
    }
    __syncthreads();
    for (int e = tid; e < 49 * 32; e += 256) {
        const int n = e >> 5, c = e & 31;
        float acc = 0.f;
        #pragma unroll 7
        for (int m2 = 0; m2 < 49; ++m2) acc = fmaf(S[n][m2], v[m2][c], acc);
        ushort hh, ll; bsplit(acc * rsum[n], hh, ll);
        oh[((size_t)lw * 49 + n) * C_DIM + h * 32 + c] = hh;
        ol[((size_t)lw * 49 + n) * C_DIM + h * 32 + c] = ll;
    }
}

// ---------------- fused MLP: LN2 + mlp1 + GELU + mlp2 + residual -------------
// One block = 64 rows of h (in d_out). Hidden (64x768) never leaves LDS.
// W1t [768][192], W2t [192][768] bf16 hi/lo pre-split (L2-resident).
// Frag layouts identical to gemm_mfma (verified): A row=l&15,k=(l>>4)*8+j;
// C/D col=l&15,row=(l>>4)*4+reg.
__global__ __launch_bounds__(256) void mlp_fused(
        float* __restrict__ out,                   // d_out, rows read+written
        const float* __restrict__ stats,
        const float* __restrict__ lng, const float* __restrict__ lnb,
        const ushort* __restrict__ W1h, const ushort* __restrict__ W1l,
        const float* __restrict__ b1,
        const ushort* __restrict__ W2h, const ushort* __restrict__ W2l,
        const float* __restrict__ b2) {
    __shared__ ushort lA[2][64][200];     // LN2'd input, hi/lo (pad 192->200)
    __shared__ ushort lH[2][64][72];      // hidden tile 64x64, hi/lo (pad->72)
    const int tid  = threadIdx.x;
    const int w    = tid >> 6;
    const int lane = tid & 63;
    const int l15  = lane & 15, l4 = lane >> 4;
    const int r0   = blockIdx.x * 64;

    // ---- stage LN2(h) into lA: thread -> row tid>>2, cols (tid&3)*48..+47
    {
        const int row = tid >> 2, c0 = (tid & 3) * 48;
        const float mu   = stats[(size_t)(r0 + row) * 2];
        const float rstd = stats[(size_t)(r0 + row) * 2 + 1];
        const float* sp = out + (size_t)(r0 + row) * C_DIM + c0;
        #pragma unroll
        for (int j = 0; j < 12; ++j) {
            float4 v = *(const float4*)(sp + j * 4);
            float4 g4 = *(const float4*)(lng + c0 + j * 4);
            float4 b4 = *(const float4*)(lnb + c0 + j * 4);
            ushort h0, l0, h1, l1, h2, l2, h3, l3;
            bsplit((v.x - mu) * rstd * g4.x + b4.x, h0, l0);
            bsplit((v.y - mu) * rstd * g4.y + b4.y, h1, l1);
            bsplit((v.z - mu) * rstd * g4.z + b4.z, h2, l2);
            bsplit((v.w - mu) * rstd * g4.w + b4.w, h3, l3);
            *(uint*)&lA[0][row][c0 + j * 4]     = (uint)h0 | ((uint)h1 << 16);
            *(uint*)&lA[0][row][c0 + j * 4 + 2] = (uint)h2 | ((uint)h3 << 16);
            *(uint*)&lA[1][row][c0 + j * 4]     = (uint)l0 | ((uint)l1 << 16);
            *(uint*)&lA[1][row][c0 + j * 4 + 2] = (uint)l2 | ((uint)l3 << 16);
        }
    }
    __syncthreads();

    f32x4 oacc[4][3];                     // 64 rows x 48 cols per wave (mlp2)
    #pragma unroll
    for (int i = 0; i < 4; ++i)
        #pragma unroll
        for (int j = 0; j < 3; ++j) oacc[i][j] = (f32x4){0.f, 0.f, 0.f, 0.f};

    for (int t = 0; t < 12; ++t) {        // hidden tiles of 64 cols
        // ---- mlp1: this wave computes 64 rows x 16 cols (t*64 + w*16 ..)
        f32x4 hacc[4];
        #pragma unroll
        for (int i = 0; i < 4; ++i) hacc[i] = (f32x4){0.f, 0.f, 0.f, 0.f};
        const int hcol = t * 64 + w * 16 + l15;      // this lane's hidden col
        #pragma unroll
        for (int ks = 0; ks < 6; ++ks) {
            const int koff = ks * 32 + l4 * 8;
            short8 bh = *(const short8*)(W1h + (size_t)hcol * 192 + koff);
            short8 bl = *(const short8*)(W1l + (size_t)hcol * 192 + koff);
            #pragma unroll
            for (int mi = 0; mi < 4; ++mi) {
                short8 ah = *(const short8*)&lA[0][mi * 16 + l15][koff];
                short8 al = *(const short8*)&lA[1][mi * 16 + l15][koff];
                hacc[mi] = __builtin_amdgcn_mfma_f32_16x16x32_bf16(ah, bh, hacc[mi], 0, 0, 0);
                hacc[mi] = __builtin_amdgcn_mfma_f32_16x16x32_bf16(ah, bl, hacc[mi], 0, 0, 0);
                hacc[mi] = __builtin_amdgcn_mfma_f32_16x16x32_bf16(al, bh, hacc[mi], 0, 0, 0);
            }
        }
        __syncthreads();                  // prev-tile mlp2 reads of lH done
        // ---- GELU + bias + split -> lH (C/D layout: row=(l4*4+reg), col=l15)
        const float b1v = b1[hcol];
        #pragma unroll
        for (int mi = 0; mi < 4; ++mi) {
            #pragma unroll
            for (int reg = 0; reg < 4; ++reg) {
                float o = hacc[mi][reg] + b1v;
                o = 0.5f * o * (1.0f + erff(o * 0.70710678118654752f));
                ushort hh, ll; bsplit(o, hh, ll);
                const int hr = mi * 16 + l4 * 4 + reg;
                lH[0][hr][w * 16 + l15] = hh;
                lH[1][hr][w * 16 + l15] = ll;
            }
        }
        __syncthreads();                  // hidden tile visible to all waves
        // ---- mlp2 partial: K-chunk = 64 (this tile); wave owns cols w*48..+47
        #pragma unroll
        for (int ks2 = 0; ks2 < 2; ++ks2) {
            const int kk = ks2 * 32 + l4 * 8;            // k within tile
            short8 amh[4], aml[4];
            #pragma unroll
            for (int mi = 0; mi < 4; ++mi) {
                amh[mi] = *(const short8*)&lH[0][mi * 16 + l15][kk];
                aml[mi] = *(const short8*)&lH[1][mi * 16 + l15][kk];
            }
            #pragma unroll
            for (int ni = 0; ni < 3; ++ni) {
                const int ocol = w * 48 + ni * 16 + l15;
                const size_t bo = (size_t)ocol * 768 + t * 64 + kk;
                short8 bh = *(const short8*)(W2h + bo);
                short8 bl = *(const short8*)(W2l + bo);
                #pragma unroll
                for (int mi = 0; mi < 4; ++mi) {
                    oacc[mi][ni] = __builtin_amdgcn_mfma_f32_16x16x32_bf16(amh[mi], bh, oacc[mi][ni], 0, 0, 0);
                    oacc[mi][ni] = __builtin_amdgcn_mfma_f32_16x16x32_bf16(amh[mi], bl, oacc[mi][ni], 0, 0, 0);
                    oacc[mi][ni] = __builtin_amdgcn_mfma_f32_16x16x32_bf16(aml[mi], bh, oacc[mi][ni], 0, 0, 0);
                }
            }
        }
        __syncthreads();                  // done reading lH before next tile
    }

    // ---- epilogue: out = oacc + b2 + h (residual), rows r0..r0+63
    #pragma unroll
    for (int ni = 0; ni < 3; ++ni) {
        const int gcol = w * 48 + ni * 16 + l15;
        const float bv = b2[gcol];
        #pragma unroll
        for (int mi = 0; mi < 4; ++mi) {
            #pragma unroll
            for (int reg = 0; reg < 4; ++reg) {
                const int grow = r0 + mi * 16 + l4 * 4 + reg;
                float* p = out + (size_t)grow * C_DIM + gcol;
                *p = oacc[mi][ni][reg] + bv + *p;
            }
        }
    }
}

// ---------------------------------------------------------------------------
extern "C" void kernel_launch(void* const* d_in, const int* in_sizes, int n_in,
                              void* d_out, int out_size, void* d_ws, size_t ws_size,
                              hipStream_t stream) {
    const float* x      = (const float*)d_in[0];
    const float* n1g    = (const float*)d_in[1];
    const float* n1b    = (const float*)d_in[2];
    const float* n2g    = (const float*)d_in[3];
    const float* n2b    = (const float*)d_in[4];
    const float* qkv_w  = (const float*)d_in[5];
    const float* qkv_b  = (const float*)d_in[6];
    const float* proj_w = (const float*)d_in[7];
    const float* proj_b = (const float*)d_in[8];
    const float* rpb    = (const float*)d_in[9];
    const float* mlp_w1 = (const float*)d_in[10];
    const float* mlp_b1 = (const float*)d_in[11];
    const float* mlp_w2 = (const float*)d_in[12];
    const float* mlp_b2 = (const float*)d_in[13];
    float* out = (float*)d_out;

    // ---- workspace: split weights (1.73 MB) | LN2 stats (803 KB) | chunkbuf
    ushort* btq_h  = (ushort*)d_ws;
    ushort* btq_l  = btq_h + 110592;
    ushort* btp_h  = btq_l + 110592;
    ushort* btp_l  = btp_h + 36864;
    ushort* btm1_h = btp_l + 36864;
    ushort* btm1_l = btm1_h + 147456;
    ushort* btm2_h = btm1_l + 147456;
    ushort* btm2_l = btm2_h + 147456;
    float*  stats2 = (float*)(btm2_l + 147456);
    char* chunkbuf = (char*)(stats2 + 2 * T_ROWS);
    const size_t fixedBytes = (size_t)2 * 884736 + (size_t)2 * T_ROWS * 4;
    const size_t avail = ws_size > fixedBytes ? ws_size - fixedBytes : 0;

    int nc = 1;
    while (nc < 8 && (size_t)(N_WIN / nc) * 49 * 3072 > avail) nc <<= 1;
    const int winC  = N_WIN / nc;
    const int rowsC = winC * 49;

    ushort* Axh  = (ushort*)chunkbuf;
    ushort* Axl  = Axh + (size_t)rowsC * C_DIM;
    float*  qkvc = (float*)(Axl + (size_t)rowsC * C_DIM);

    const dim3 blk(256);

    // 0. split + transpose weights
    split_w<<<dim3((192 * 576 + 255) / 256), blk, 0, stream>>>(qkv_w,  btq_h,  btq_l,  192, 576);
    split_w<<<dim3((192 * 192 + 255) / 256), blk, 0, stream>>>(proj_w, btp_h,  btp_l,  192, 192);
    split_w<<<dim3((192 * 768 + 255) / 256), blk, 0, stream>>>(mlp_w1, btm1_h, btm1_l, 192, 768);
    split_w<<<dim3((768 * 192 + 255) / 256), blk, 0, stream>>>(mlp_w2, btm2_h, btm2_l, 768, 192);

    // 1-4. attention path (chunked over windows), h -> d_out
    for (int c = 0; c < nc; ++c) {
        const int row_off = c * rowsC;
        ln1_split<<<dim3(rowsC / 4), blk, 0, stream>>>(x, n1g, n1b, Axh, Axl, row_off);
        gemm_mfma<0><<<dim3(9, rowsC / 256), blk, 0, stream>>>(
            Axh, Axl, btq_h, btq_l, qkv_b, qkvc, 192, 576, 576, nullptr, row_off);
        attn_kernel<<<dim3(winC * 6), blk, 0, stream>>>(qkvc, rpb, Axh, Axl, c * winC);
        gemm_mfma<1><<<dim3(3, rowsC / 256), blk, 0, stream>>>(
            Axh, Axl, btp_h, btp_l, proj_b, out, 192, 192, 192, x, row_off);
    }

    // 5. LN2 stats on h
    ln_stats<<<dim3(T_ROWS / 4), blk, 0, stream>>>(out, stats2);

    // 6. fused MLP (hidden stays in LDS), finishes d_out in place
    mlp_fused<<<dim3(T_ROWS / 64), blk, 0, stream>>>(
        out, stats2, n2g, n2b, btm1_h, btm1_l, mlp_b1, btm2_h, btm2_l, mlp_b2);
}